// Round 5
// baseline (309.785 us; speedup 1.0000x reference)
//
#include <hip/hip_runtime.h>

typedef __bf16 bf16_t;
typedef __bf16 v8bf __attribute__((ext_vector_type(8)));
typedef __bf16 v4bf __attribute__((ext_vector_type(4)));
typedef float  v4f  __attribute__((ext_vector_type(4)));

#define D_MODEL 1024
#define NHEAD   16
#define DHEAD   64
#define SEQ     2048
#define BATCH   4
#define ROWS    (BATCH*SEQ)   // 8192

// async global->LDS, 16B per lane; LDS dest MUST be wave-uniform:
// HW writes base + lane*16 (guide §5: not a per-lane scatter).
#define GLD16(g, l) __builtin_amdgcn_global_load_lds( \
    (const __attribute__((address_space(1))) void*)(g), \
    (__attribute__((address_space(3))) void*)(l), 16, 0, 0)

// ---------------------------------------------------------------- fused prep (casts + bias pack)
__global__ __launch_bounds__(256) void k_prep(const float* __restrict__ batch,
                                              const float* __restrict__ wq,
                                              const float* __restrict__ wk,
                                              const float* __restrict__ wv,
                                              const float* __restrict__ wo,
                                              const float* __restrict__ bq,
                                              const float* __restrict__ bk,
                                              const float* __restrict__ bv,
                                              bf16_t* __restrict__ Xb,
                                              bf16_t* __restrict__ Wqkv,
                                              bf16_t* __restrict__ Wob,
                                              float* __restrict__ bqkv) {
    int bid = blockIdx.x, t = threadIdx.x;
    const float* src; bf16_t* dst; int idx;
    if (bid < 8192)       { src = batch; dst = Xb;             idx = bid * 256 + t; }
    else if (bid < 9216)  { src = wq;    dst = Wqkv;           idx = (bid - 8192) * 256 + t; }
    else if (bid < 10240) { src = wk;    dst = Wqkv + 1048576; idx = (bid - 9216) * 256 + t; }
    else if (bid < 11264) { src = wv;    dst = Wqkv + 2097152; idx = (bid - 10240) * 256 + t; }
    else if (bid < 12288) { src = wo;    dst = Wob;            idx = (bid - 11264) * 256 + t; }
    else {
        int i = (bid - 12288) * 256 + t;   // 0..3071
        if (i < 1024) bqkv[i] = bq[i];
        else if (i < 2048) bqkv[i] = bk[i - 1024];
        else if (i < 3072) bqkv[i] = bv[i - 2048];
        return;
    }
    float4 f = ((const float4*)src)[idx];
    v4bf o;
    o[0] = (bf16_t)f.x; o[1] = (bf16_t)f.y; o[2] = (bf16_t)f.z; o[3] = (bf16_t)f.w;
    ((v4bf*)dst)[idx] = o;
}

// ---------------------------------------------------------------- wide-N GEMM (QKV): C = A*B^T (+bias, qmul)
// Round 15: BM=128 BN=256 BK=32, 256 thr (4 waves 2Mx2N), wave output
// 64x128 = acc[4][8]. Rationale (R4 post-mortem):
//  - per-wave read:MFMA = 12:32 (vs 8:16 at 64x64) -> LDS pipe demand
//    (12 reads x 12cyc x 8 waves = 1152 cyc/CU/K32) < MFMA demand
//    (8 x 32 x 4.85 = 1241) -> MFMA-limited structure.
//  - grid 64x12 = 768 blocks = exactly 3 blocks/CU of work, LDS 72KB ->
//    2 blocks/CU resident: NO grid tail (R4's 384@1/CU lost ~25%).
//  - schedule/swizzle copied VERBATIM from the proven 75.7us k_gemm_bt:
//    3-buffer rotation, stage tile t+2 after barrier, counted vmcnt(6)
//    (6 GLD16/thread/tile: A 2 + B 4; outstanding {t,t+1}=12, drain 6).
//    g(row)=(row>>1)&3 swizzle: 8-consecutive-lane groups (the 128B bank
//    sweep of a wave64 b128 read) hit 8 DISTINCT 16B slots (R4's row&3
//    repeated 4 slots twice -> measured exactly 4 conflicts/read).
__global__ __launch_bounds__(256, 2) void k_gemm_bt2(
    const bf16_t* __restrict__ A, const bf16_t* __restrict__ Bm,
    const float* __restrict__ bias, bf16_t* __restrict__ Cb,
    int M, int N, int K, int qcols, float qmul)
{
    __shared__ bf16_t As[3][128 * 32];   // 24 KB
    __shared__ bf16_t Bs[3][256 * 32];   // 48 KB

    int nT = N >> 8;                          // 256-wide n-tiles
    int cpx = ((M >> 7) * nT) >> 3;           // blocks per XCD chunk
    int bid = blockIdx.x;
    int wg = (bid & 7) * cpx + (bid >> 3);    // XCD-chunked (768 = 8 x 96)
    int m_idx = wg / nT, n_idx = wg % nT;
    int m0 = m_idx << 7, n0 = n_idx << 8;

    int t = threadIdx.x;
    int w = t >> 6, lane = t & 63, quad = lane >> 4, ln = lane & 15;
    int wm = (w >> 1) << 6, wn = (w & 1) << 7;

    // staging: instr covers 16 rows (srow = lane>>2), phys chunk lane&3,
    // logical chunk = (lane&3) ^ g(row), g(row) = (row>>1)&3 = (lane>>3)&3
    int srow = lane >> 2;
    int scol = ((lane & 3) ^ ((lane >> 3) & 3)) << 3;
    const bf16_t* Ag0 = A  + (size_t)(m0 + w * 16 + srow) * K + scol;
    const bf16_t* Ag1 = Ag0 + (size_t)64 * K;
    const bf16_t* Bg0 = Bm + (size_t)(n0 + w * 16 + srow) * K + scol;
    const bf16_t* Bg1 = Bg0 + (size_t)64 * K;
    const bf16_t* Bg2 = Bg0 + (size_t)128 * K;
    const bf16_t* Bg3 = Bg0 + (size_t)192 * K;
    int la0 = (w * 16) * 32, la1 = (w * 16 + 64) * 32;
    int lb0 = (w * 16) * 32;   // B instr i at lb0 + i*2048 (rows w*16 + 64i)

    v4f acc[4][8];
#pragma unroll
    for (int i = 0; i < 4; i++)
#pragma unroll
        for (int j = 0; j < 8; j++) acc[i][j] = (v4f){0.f, 0.f, 0.f, 0.f};

    bf16_t* aPrev = As[2]; bf16_t* aCur = As[0]; bf16_t* aNext = As[1];
    bf16_t* bPrev = Bs[2]; bf16_t* bCur = Bs[0]; bf16_t* bNext = Bs[1];

    // prologue: tile0 -> buf0, tile1 -> buf1 (12 loads outstanding)
    GLD16(Ag0, aCur + la0); GLD16(Ag1, aCur + la1);
    GLD16(Bg0, bCur + lb0); GLD16(Bg1, bCur + lb0 + 2048);
    GLD16(Bg2, bCur + lb0 + 4096); GLD16(Bg3, bCur + lb0 + 6144);
    GLD16(Ag0 + 32, aNext + la0); GLD16(Ag1 + 32, aNext + la1);
    GLD16(Bg0 + 32, bNext + lb0); GLD16(Bg1 + 32, bNext + lb0 + 2048);
    GLD16(Bg2 + 32, bNext + lb0 + 4096); GLD16(Bg3 + 32, bNext + lb0 + 6144);

    int rsw = (quad ^ ((ln >> 1) & 3)) << 3;   // read-side swizzle
    for (int k0 = 0; k0 < K; k0 += 32) {
        if (k0 + 32 < K) asm volatile("s_waitcnt vmcnt(6)" ::: "memory");
        else             asm volatile("s_waitcnt vmcnt(0)" ::: "memory");
        __builtin_amdgcn_s_barrier();
        __builtin_amdgcn_sched_barrier(0);
        if (k0 + 64 < K) {
            GLD16(Ag0 + k0 + 64, aPrev + la0);
            GLD16(Ag1 + k0 + 64, aPrev + la1);
            GLD16(Bg0 + k0 + 64, bPrev + lb0);
            GLD16(Bg1 + k0 + 64, bPrev + lb0 + 2048);
            GLD16(Bg2 + k0 + 64, bPrev + lb0 + 4096);
            GLD16(Bg3 + k0 + 64, bPrev + lb0 + 6144);
        }
        v8bf af[4], bfr[8];
#pragma unroll
        for (int mt = 0; mt < 4; mt++)
            af[mt] = *(const v8bf*)&aCur[(wm + mt * 16 + ln) * 32 + rsw];
#pragma unroll
        for (int nt = 0; nt < 8; nt++)
            bfr[nt] = *(const v8bf*)&bCur[(wn + nt * 16 + ln) * 32 + rsw];
#pragma unroll
        for (int mt = 0; mt < 4; mt++)
#pragma unroll
            for (int nt = 0; nt < 8; nt++)
                acc[mt][nt] = __builtin_amdgcn_mfma_f32_16x16x32_bf16(af[mt], bfr[nt], acc[mt][nt], 0, 0, 0);
        bf16_t* ta = aPrev; aPrev = aCur; aCur = aNext; aNext = ta;
        bf16_t* tb = bPrev; bPrev = bCur; bCur = bNext; bNext = tb;
    }

#pragma unroll
    for (int mt = 0; mt < 4; mt++) {
#pragma unroll
        for (int r = 0; r < 4; r++) {
            int row = m0 + wm + mt * 16 + quad * 4 + r;
#pragma unroll
            for (int nt = 0; nt < 8; nt++) {
                int col = n0 + wn + nt * 16 + ln;
                float v = acc[mt][nt][r] + bias[col];
                if (col < qcols) v *= qmul;
                Cb[(size_t)row * N + col] = (bf16_t)v;
            }
        }
    }
}

// ---------------------------------------------------------------- GEMM  C = A * B^T (+bias) (+resid)
// (proj GEMM: N=1024 -> 512 128x128 tiles = 2/CU balanced at 3/CU
// residency; keep the proven 128x128 3-buffer counted-vmcnt structure.)
__global__ __launch_bounds__(256, 3) void k_gemm_bt(
    const bf16_t* __restrict__ A, const bf16_t* __restrict__ Bm,
    const float* __restrict__ bias, const float* __restrict__ resid,
    bf16_t* __restrict__ Cb, float* __restrict__ Cf,
    int M, int N, int K, int qcols, float qmul)
{
    __shared__ bf16_t As[3][128 * 32];
    __shared__ bf16_t Bs[3][128 * 32];

    int nTile = N >> 7;
    int x = blockIdx.x & 7, g = blockIdx.x >> 3;
    int n_idx = g % nTile;
    int m_idx = (g / nTile) * 8 + x;
    int m0 = m_idx << 7;
    int n0 = n_idx << 7;
    int t = threadIdx.x;
    int w = t >> 6, lane = t & 63, quad = lane >> 4, ln = lane & 15;
    int wm = (w >> 1) << 6, wn = (w & 1) << 6;

    int srow = lane >> 2;                               // 0..15
    int scol = ((lane & 3) ^ ((lane >> 3) & 3)) << 3;   // swizzled logical chunk *8
    const bf16_t* Ag0 = A  + (size_t)(m0 + w * 16 +      srow) * K + scol;
    const bf16_t* Ag1 = A  + (size_t)(m0 + w * 16 + 64 + srow) * K + scol;
    const bf16_t* Bg0 = Bm + (size_t)(n0 + w * 16 +      srow) * K + scol;
    const bf16_t* Bg1 = Bm + (size_t)(n0 + w * 16 + 64 + srow) * K + scol;
    int lo0 = (w * 16) * 32, lo1 = (w * 16 + 64) * 32;

    v4f acc[4][4];
#pragma unroll
    for (int i = 0; i < 4; i++)
#pragma unroll
        for (int j = 0; j < 4; j++) acc[i][j] = (v4f){0.f, 0.f, 0.f, 0.f};

    bf16_t* aPrev = As[2]; bf16_t* aCur = As[0]; bf16_t* aNext = As[1];
    bf16_t* bPrev = Bs[2]; bf16_t* bCur = Bs[0]; bf16_t* bNext = Bs[1];

    GLD16(Ag0, aCur + lo0);
    GLD16(Ag1, aCur + lo1);
    GLD16(Bg0, bCur + lo0);
    GLD16(Bg1, bCur + lo1);
    GLD16(Ag0 + 32, aNext + lo0);
    GLD16(Ag1 + 32, aNext + lo1);
    GLD16(Bg0 + 32, bNext + lo0);
    GLD16(Bg1 + 32, bNext + lo1);

    int sw = (ln >> 1) & 3;   // read-side swizzle
    for (int k0 = 0; k0 < K; k0 += 32) {
        if (k0 + 32 < K) asm volatile("s_waitcnt vmcnt(4)" ::: "memory");
        else             asm volatile("s_waitcnt vmcnt(0)" ::: "memory");
        __builtin_amdgcn_s_barrier();
        __builtin_amdgcn_sched_barrier(0);
        if (k0 + 64 < K) {
            GLD16(Ag0 + k0 + 64, aPrev + lo0);
            GLD16(Ag1 + k0 + 64, aPrev + lo1);
            GLD16(Bg0 + k0 + 64, bPrev + lo0);
            GLD16(Bg1 + k0 + 64, bPrev + lo1);
        }
        v8bf af[4], bfr[4];
#pragma unroll
        for (int mt = 0; mt < 4; mt++)
            af[mt] = *(const v8bf*)&aCur[(wm + mt * 16 + ln) * 32 + ((quad ^ sw) << 3)];
#pragma unroll
        for (int nt = 0; nt < 4; nt++)
            bfr[nt] = *(const v8bf*)&bCur[(wn + nt * 16 + ln) * 32 + ((quad ^ sw) << 3)];
#pragma unroll
        for (int mt = 0; mt < 4; mt++)
#pragma unroll
            for (int nt = 0; nt < 4; nt++)
                acc[mt][nt] = __builtin_amdgcn_mfma_f32_16x16x32_bf16(af[mt], bfr[nt], acc[mt][nt], 0, 0, 0);
        bf16_t* ta = aPrev; aPrev = aCur; aCur = aNext; aNext = ta;
        bf16_t* tb = bPrev; bPrev = bCur; bCur = bNext; bNext = tb;
    }

#pragma unroll
    for (int mt = 0; mt < 4; mt++) {
#pragma unroll
        for (int r = 0; r < 4; r++) {
            int row = m0 + wm + mt * 16 + quad * 4 + r;
#pragma unroll
            for (int nt = 0; nt < 4; nt++) {
                int col = n0 + wn + nt * 16 + ln;
                float v = acc[mt][nt][r] + bias[col];
                if (Cf) Cf[(size_t)row * N + col] = v + resid[(size_t)row * N + col];
                else {
                    if (col < qcols) v *= qmul;
                    Cb[(size_t)row * N + col] = (bf16_t)v;
                }
            }
        }
    }
}

// ---------------------------------------------------------------- V transpose: qkv V-cols -> Vt[bh][d][s]
__global__ __launch_bounds__(256) void k_transpose_v(const bf16_t* __restrict__ qkv,
                                                     bf16_t* __restrict__ vt) {
    __shared__ bf16_t tile[64 * 72];
    int bid = blockIdx.x;
    int st = bid & 31, bh = bid >> 5, b = bh >> 4, h = bh & 15;
    int t = threadIdx.x;
    const bf16_t* src = qkv + (size_t)(b * SEQ + st * 64) * 3072 + 2048 + h * 64;
#pragma unroll
    for (int i = 0; i < 2; i++) {
        int c = t + i * 256, row = c >> 3, c8 = (c & 7) << 3;
        *(uint4*)&tile[row * 72 + c8] = *(const uint4*)(src + (size_t)row * 3072 + c8);
    }
    __syncthreads();
    bf16_t* dst = vt + (size_t)bh * DHEAD * SEQ + st * 64;
#pragma unroll
    for (int i = 0; i < 2; i++) {
        int c = t + i * 256, d = c >> 3, s8 = (c & 7) << 3;
        v8bf o;
#pragma unroll
        for (int j = 0; j < 8; j++) o[j] = tile[(s8 + j) * 72 + d];
        *(v8bf*)(dst + (size_t)d * SEQ + s8) = o;
    }
}

// ---------------------------------------------------------------- attention (register-resident P)
// R15: V gets its own swizzle g(row)=row&7 (V-read rows d*16+ln vary in
// all 4 low bits of ln -> row&7 is distinct across each 8-consecutive-lane
// group = conflict-free b128). The old shared gv repeated 4 slots twice
// per group (2-way conflict on every V read). K swizzle unchanged
// (verified distinct: gk spans 0..7 within each lane group).
__global__ __launch_bounds__(256, 2) void k_attn(const bf16_t* __restrict__ qkv,
                                                 const bf16_t* __restrict__ vt,
                                                 bf16_t* __restrict__ attn) {
    __shared__ bf16_t Ks[2][64 * 64];
    __shared__ bf16_t Vs[2][64 * 64];

    int bid = blockIdx.x;
    int xcd = bid & 7, g = bid >> 3;
    int qt = g & 15;
    int bh = ((g >> 4) << 3) | xcd;
    int b = bh >> 4, h = bh & 15;
    int t = threadIdx.x, w = t >> 6, lane = t & 63, quad = lane >> 4, ln = lane & 15;
    int q0 = qt * 128 + w * 32;

    v8bf qf[2][2];
#pragma unroll
    for (int qs = 0; qs < 2; qs++) {
        const bf16_t* Qp = qkv + (size_t)(b * SEQ + q0 + qs * 16 + ln) * 3072 + h * 64 + quad * 8;
        qf[qs][0] = *(const v8bf*)Qp;
        qf[qs][1] = *(const v8bf*)(Qp + 32);
    }

    int srow = lane >> 3;                        // 0..7
    // K store: g(row) = (row&3)|((row>>3&1)<<2) = ((lane>>3)&3)|((w&1)<<2)
    int scolK = ((lane & 7) ^ ((lane >> 3) & 3) ^ ((w & 1) << 2)) << 3;
    // V store: g(row) = row&7 = lane>>3
    int scolV = ((lane & 7) ^ (lane >> 3)) << 3;
    const bf16_t* Kg0 = qkv + (size_t)(b * SEQ + w * 8 +      srow) * 3072 + 1024 + h * 64 + scolK;
    const bf16_t* Kg1 = qkv + (size_t)(b * SEQ + w * 8 + 32 + srow) * 3072 + 1024 + h * 64 + scolK;
    const bf16_t* Vg0 = vt + (size_t)bh * DHEAD * SEQ + (size_t)(w * 8 +      srow) * SEQ + scolV;
    const bf16_t* Vg1 = vt + (size_t)bh * DHEAD * SEQ + (size_t)(w * 8 + 32 + srow) * SEQ + scolV;
    int ko0 = (w * 8) * 64, ko1 = (w * 8 + 32) * 64;

    int gk = (ln & 3) | (((ln >> 2) & 1) << 2);   // K rows rr: rr&3=ln&3, rr>>3&1=(ln>>2)&1
    int gv = ln & 7;                              // V rows d*16+ln: row&7 = ln&7
    int rrbase = ((ln >> 2) << 3) + (ln & 3);       // 8*(ln>>2) + (ln&3)
    int o0 = (rrbase) * 64,       o1 = (rrbase + 4) * 64;        // nt 0 / 1 row offsets
    int o2 = (rrbase + 32) * 64,  o3 = (rrbase + 36) * 64;       // nt 2 / 3

    const v4f z4 = (v4f){0.f, 0.f, 0.f, 0.f};
    v8bf ones8;
#pragma unroll
    for (int j = 0; j < 8; j++) ones8[j] = (bf16_t)1.0f;

    v4f o[2][4];
#pragma unroll
    for (int qs = 0; qs < 2; qs++)
#pragma unroll
        for (int d = 0; d < 4; d++) o[qs][d] = z4;
    v4f den[2] = {z4, z4};

    // prologue: tile 0 -> buf 0
    GLD16(Kg0, &Ks[0][ko0]);
    GLD16(Kg1, &Ks[0][ko1]);
    GLD16(Vg0, &Vs[0][ko0]);
    GLD16(Vg1, &Vs[0][ko1]);

    int buf = 0;
    for (int kt = 0; kt < SEQ; kt += 64, buf ^= 1) {
        __syncthreads();   // vmcnt(0) drain covers tile-kt loads (issued last iter)
        if (kt + 64 < SEQ) {
            GLD16(Kg0 + (size_t)(kt + 64) * 3072, &Ks[buf ^ 1][ko0]);
            GLD16(Kg1 + (size_t)(kt + 64) * 3072, &Ks[buf ^ 1][ko1]);
            GLD16(Vg0 + kt + 64, &Vs[buf ^ 1][ko0]);
            GLD16(Vg1 + kt + 64, &Vs[buf ^ 1][ko1]);
        }

        // S^T = K * Q^T; tile nt rows at permuted offsets (key map in header)
        const bf16_t* Kb = &Ks[buf][0];
        v4f s0[4], s1[4];
        int rof[4] = {o0, o1, o2, o3};
#pragma unroll
        for (int nt = 0; nt < 4; nt++) {
            v8bf kf0 = *(const v8bf*)&Kb[rof[nt] + ((quad ^ gk) << 3)];
            v8bf kf1 = *(const v8bf*)&Kb[rof[nt] + (((quad | 4) ^ gk) << 3)];
            s0[nt] = __builtin_amdgcn_mfma_f32_16x16x32_bf16(kf0, qf[0][0], z4, 0, 0, 0);
            s0[nt] = __builtin_amdgcn_mfma_f32_16x16x32_bf16(kf1, qf[0][1], s0[nt], 0, 0, 0);
            s1[nt] = __builtin_amdgcn_mfma_f32_16x16x32_bf16(kf0, qf[1][0], z4, 0, 0, 0);
            s1[nt] = __builtin_amdgcn_mfma_f32_16x16x32_bf16(kf1, qf[1][1], s1[nt], 0, 0, 0);
        }

        // PV: P assembled in-register from s (lane's own values)
#pragma unroll
        for (int tk = 0; tk < 2; tk++) {
            v8bf vfd[4];
#pragma unroll
            for (int d = 0; d < 4; d++)
                vfd[d] = *(const v8bf*)&Vs[buf][(d * 16 + ln) * 64 + (((tk * 4 + quad) ^ gv) << 3)];
#pragma unroll
            for (int qs = 0; qs < 2; qs++) {
                v4f* s = qs ? s1 : s0;
                float e0 = __builtin_amdgcn_exp2f(s[2 * tk][0]);
                float e1 = __builtin_amdgcn_exp2f(s[2 * tk][1]);
                float e2 = __builtin_amdgcn_exp2f(s[2 * tk][2]);
                float e3 = __builtin_amdgcn_exp2f(s[2 * tk][3]);
                float e4 = __builtin_amdgcn_exp2f(s[2 * tk + 1][0]);
                float e5 = __builtin_amdgcn_exp2f(s[2 * tk + 1][1]);
                float e6 = __builtin_amdgcn_exp2f(s[2 * tk + 1][2]);
                float e7 = __builtin_amdgcn_exp2f(s[2 * tk + 1][3]);
                v8bf pf;
                pf[0] = (bf16_t)e0; pf[1] = (bf16_t)e1; pf[2] = (bf16_t)e2; pf[3] = (bf16_t)e3;
                pf[4] = (bf16_t)e4; pf[5] = (bf16_t)e5; pf[6] = (bf16_t)e6; pf[7] = (bf16_t)e7;
                den[qs] = __builtin_amdgcn_mfma_f32_16x16x32_bf16(pf, ones8, den[qs], 0, 0, 0);
#pragma unroll
                for (int d = 0; d < 4; d++)
                    o[qs][d] = __builtin_amdgcn_mfma_f32_16x16x32_bf16(pf, vfd[d], o[qs][d], 0, 0, 0);
            }
        }
    }

#pragma unroll
    for (int qs = 0; qs < 2; qs++) {
        int rowg = b * SEQ + q0 + qs * 16;
#pragma unroll
        for (int r = 0; r < 4; r++) {
            float inv = 1.f / den[qs][r];
#pragma unroll
            for (int d = 0; d < 4; d++)
                attn[(size_t)(rowg + quad * 4 + r) * D_MODEL + h * 64 + d * 16 + ln] =
                    (bf16_t)(o[qs][d][r] * inv);
        }
    }
}

// ---------------------------------------------------------------- LayerNorm (one row / block)
__global__ __launch_bounds__(256) void k_layernorm(const float* __restrict__ y,
                                                   const float* __restrict__ g,
                                                   const float* __restrict__ beta,
                                                   float* __restrict__ out) {
    __shared__ float rs[4], rq[4];
    int row = blockIdx.x, t = threadIdx.x;
    int w = t >> 6, lane = t & 63;
    float4 v = ((const float4*)(y + (size_t)row * D_MODEL))[t];
    float s = v.x + v.y + v.z + v.w;
    float q = v.x * v.x + v.y * v.y + v.z * v.z + v.w * v.w;
#pragma unroll
    for (int off = 1; off < 64; off <<= 1) {
        s += __shfl_xor(s, off);
        q += __shfl_xor(q, off);
    }
    if (lane == 0) { rs[w] = s; rq[w] = q; }
    __syncthreads();
    s = rs[0] + rs[1] + rs[2] + rs[3];
    q = rq[0] + rq[1] + rq[2] + rq[3];
    float mu = s * (1.f / D_MODEL);
    float var = q * (1.f / D_MODEL) - mu * mu;
    float rstd = rsqrtf(var + 1e-5f);
    float4 gg = ((const float4*)g)[t];
    float4 bb = ((const float4*)beta)[t];
    float4 o;
    o.x = (v.x - mu) * rstd * gg.x + bb.x;
    o.y = (v.y - mu) * rstd * gg.y + bb.y;
    o.z = (v.z - mu) * rstd * gg.z + bb.z;
    o.w = (v.w - mu) * rstd * gg.w + bb.w;
    ((float4*)(out + (size_t)row * D_MODEL))[t] = o;
}

// ---------------------------------------------------------------- launch
extern "C" void kernel_launch(void* const* d_in, const int* in_sizes, int n_in,
                              void* d_out, int out_size, void* d_ws, size_t ws_size,
                              hipStream_t stream) {
    const float* batch = (const float*)d_in[0];
    const float* wq = (const float*)d_in[1];
    const float* bq = (const float*)d_in[2];
    const float* wk = (const float*)d_in[3];
    const float* bk = (const float*)d_in[4];
    const float* wv = (const float*)d_in[5];
    const float* bv = (const float*)d_in[6];
    const float* wo = (const float*)d_in[7];
    const float* bo = (const float*)d_in[8];
    const float* ln_g = (const float*)d_in[9];
    const float* ln_b = (const float*)d_in[10];
    float* out = (float*)d_out;

    char* ws = (char*)d_ws;
    size_t offXb   = 0;                                          // bf16 X (later Vt)
    size_t offWqkv = offXb + (size_t)ROWS * D_MODEL * 2;
    size_t offWo   = offWqkv + (size_t)3072 * 1024 * 2;
    size_t offBias = offWo + (size_t)1024 * 1024 * 2;
    size_t offQKV  = offBias + 3072 * 4;                         // bf16 qkv (later fp32 y)
    size_t offAttn = offQKV + (size_t)ROWS * 3072 * 2;
    size_t total   = offAttn + (size_t)ROWS * D_MODEL * 2;       // = 92,286,976
    if (ws_size < total) return;

    bf16_t* Xb   = (bf16_t*)(ws + offXb);
    bf16_t* Vt   = (bf16_t*)(ws + offXb);
    bf16_t* Wqkv = (bf16_t*)(ws + offWqkv);
    bf16_t* Wob  = (bf16_t*)(ws + offWo);
    float*  bqkv = (float*)(ws + offBias);
    bf16_t* qkv  = (bf16_t*)(ws + offQKV);
    float*  y    = (float*)(ws + offQKV);
    bf16_t* attn = (bf16_t*)(ws + offAttn);

    const float SC = 0.125f * 1.44269504088896f;  // 1/sqrt(64) * log2(e), folded into Q

    k_prep<<<12300, 256, 0, stream>>>(batch, wq, wk, wv, wo, bq, bk, bv,
                                      Xb, Wqkv, Wob, bqkv);
    k_gemm_bt2<<<768, 256, 0, stream>>>(Xb, Wqkv, bqkv, qkv,
                                        8192, 3072, 1024, 1024, SC);
    k_transpose_v<<<2048, 256, 0, stream>>>(qkv, Vt);
    k_attn<<<1024, 256, 0, stream>>>(qkv, Vt, attn);
    k_gemm_bt<<<64 * 8, 256, 0, stream>>>(attn, Wob, bo, batch, nullptr, y,
                                          8192, 1024, 1024, 0, 1.0f);
    k_layernorm<<<8192, 256, 0, stream>>>(y, ln_g, ln_b, out);
}

// Round 6
// 304.195 us; speedup vs baseline: 1.0184x; 1.0184x over previous
//
#include <hip/hip_runtime.h>

typedef __bf16 bf16_t;
typedef __bf16 v8bf __attribute__((ext_vector_type(8)));
typedef __bf16 v4bf __attribute__((ext_vector_type(4)));
typedef float  v4f  __attribute__((ext_vector_type(4)));

#define D_MODEL 1024
#define NHEAD   16
#define DHEAD   64
#define SEQ     2048
#define BATCH   4
#define ROWS    (BATCH*SEQ)   // 8192

// async global->LDS, 16B per lane; LDS dest MUST be wave-uniform:
// HW writes base + lane*16 (guide §5: not a per-lane scatter).
#define GLD16(g, l) __builtin_amdgcn_global_load_lds( \
    (const __attribute__((address_space(1))) void*)(g), \
    (__attribute__((address_space(3))) void*)(l), 16, 0, 0)

#define BAR asm volatile("s_barrier" ::: "memory")

// ---------------------------------------------------------------- fused prep (casts + bias pack)
__global__ __launch_bounds__(256) void k_prep(const float* __restrict__ batch,
                                              const float* __restrict__ wq,
                                              const float* __restrict__ wk,
                                              const float* __restrict__ wv,
                                              const float* __restrict__ wo,
                                              const float* __restrict__ bq,
                                              const float* __restrict__ bk,
                                              const float* __restrict__ bv,
                                              bf16_t* __restrict__ Xb,
                                              bf16_t* __restrict__ Wqkv,
                                              bf16_t* __restrict__ Wob,
                                              float* __restrict__ bqkv) {
    int bid = blockIdx.x, t = threadIdx.x;
    const float* src; bf16_t* dst; int idx;
    if (bid < 8192)       { src = batch; dst = Xb;             idx = bid * 256 + t; }
    else if (bid < 9216)  { src = wq;    dst = Wqkv;           idx = (bid - 8192) * 256 + t; }
    else if (bid < 10240) { src = wk;    dst = Wqkv + 1048576; idx = (bid - 9216) * 256 + t; }
    else if (bid < 11264) { src = wv;    dst = Wqkv + 2097152; idx = (bid - 10240) * 256 + t; }
    else if (bid < 12288) { src = wo;    dst = Wob;            idx = (bid - 11264) * 256 + t; }
    else {
        int i = (bid - 12288) * 256 + t;   // 0..3071
        if (i < 1024) bqkv[i] = bq[i];
        else if (i < 2048) bqkv[i] = bk[i - 1024];
        else if (i < 3072) bqkv[i] = bv[i - 2048];
        return;
    }
    float4 f = ((const float4*)src)[idx];
    v4bf o;
    o[0] = (bf16_t)f.x; o[1] = (bf16_t)f.y; o[2] = (bf16_t)f.z; o[3] = (bf16_t)f.w;
    ((v4bf*)dst)[idx] = o;
}

// ---------------------------------------------------------------- 256x256 pipelined 4-phase GEMM (QKV)
// C = A * B^T (+bias, qmul on first 1024 cols). M=8192 N=3072 K=1024 HARDCODED.
// BM=BN=256, BK=64 (2 K-halves of 32), 512 thr = 8 waves (wr=w>>2 picks
// A-rows wr*128+128, wc=w&3 picks B-rows wc*64+64), acc[8][4].
// LDS 128 KiB: As/Bs[2 tile-buf][2 K-half][256x32].
// R6 fixes over R4 (78.7us, MfmaUtil 26%, 4.7M conflicts):
//  (1) swizzle g(row)=(row>>1)&3 both sides: 8-lane-group (128B sweep)
//      slot pattern {0,4,1,5,2,6,3,7} = conflict-free (R4's row&3 gave
//      {0,5,2,7}x2 = 2-way = measured 4 extra cyc/read).
//  (2) fragment reads pipelined ONE PHASE AHEAD: phase p = {stage GLD;
//      ds_read p+1's frags; MFMA p (setprio); tail}. One barrier/phase
//      (4/tile, was 8). ds_reads overlap MFMA; lgkmcnt inserted by
//      compiler covers the in-flight reads.
//  (3) vmcnt drains shifted to P1/P3 tails so every body-read's slot is
//      drained one phase before it's read. FIFO ledger (2 loads/stage,
//      verified): prologue 12 -> vmcnt(8); steady P1: +2 -> vmcnt(6)
//      drains (tau)kh1; P3: +2 -> vmcnt(6) drains (tau+1)kh0; peel
//      t14: 6/4, t15: 0. Slot write-after-read safety: readers' ds_reads
//      drain (lgkm) before their MFMA < their tail barrier < writer's
//      stage issue (>=1 barrier separation, every pair checked).
// Stage schedule per tile tau: P1 A(tau+1)kh1, P2 B(tau+1)kh1,
// P3 A(tau+2)kh0, P4 B(tau+2)kh0. Grid 384 @ 1 block/CU (1.5 rounds).
__global__ __launch_bounds__(512, 2) void k_gemm256(
    const bf16_t* __restrict__ A, const bf16_t* __restrict__ Bm,
    const float* __restrict__ bias, bf16_t* __restrict__ C, float qmul)
{
    __shared__ bf16_t As[2][2][256 * 32];
    __shared__ bf16_t Bs[2][2][256 * 32];

    const int K = 1024;
    int bid = blockIdx.x;
    int wg = (bid & 7) * 48 + (bid >> 3);      // XCD-chunked: 384 = 8 x 48
    int m_idx = wg / 12, n_idx = wg % 12;
    int m0 = m_idx << 8, n0 = n_idx << 8;

    int t = threadIdx.x;
    int lane = t & 63, quad = lane >> 4, ln = lane & 15;
    int w = t >> 6, wr = w >> 2, wc = w & 3;

    // staging: thread covers rows t>>2 and (t>>2)+128, phys chunk t&3;
    // logical chunk = (t&3) ^ g(row), g(row)=(row>>1)&3 = (t>>3)&3
    int cl = (t & 3) ^ ((t >> 3) & 3);
    const bf16_t* Ag = A  + (size_t)(m0 + (t >> 2)) * K + cl * 8;
    const bf16_t* Bg = Bm + (size_t)(n0 + (t >> 2)) * K + cl * 8;
    int wb = w << 9;                            // wave-uniform LDS base

#define STA(bufv, khv, kc) { const bf16_t* g_ = Ag + (kc) + ((khv) << 5); \
    GLD16(g_, &As[bufv][khv][wb]); GLD16(g_ + 131072, &As[bufv][khv][wb + 4096]); }
#define STB(bufv, khv, kc) { const bf16_t* g_ = Bg + (kc) + ((khv) << 5); \
    GLD16(g_, &Bs[bufv][khv][wb]); GLD16(g_ + 131072, &Bs[bufv][khv][wb + 4096]); }

    // read: row*32 + ((quad ^ ((row>>1)&3))<<3); row-in-16-group == ln
    int rsw = (quad ^ ((ln >> 1) & 3)) << 3;
    int aofs = (wr * 128 + ln) * 32 + rsw;
    int bofs = (wc * 64 + ln) * 32 + rsw;

#define LDA(dst, bufv, mhv) { \
    dst[0] = *(const v8bf*)&AB_[aofs + (mhv) * 2048]; \
    dst[1] = *(const v8bf*)&AB_[aofs + (mhv) * 2048 + 512]; \
    dst[2] = *(const v8bf*)&AB_[aofs + (mhv) * 2048 + 1024]; \
    dst[3] = *(const v8bf*)&AB_[aofs + (mhv) * 2048 + 1536]; }
#define LDAF(dst, bufv, khv, mhv) { const bf16_t* AB_ = &As[bufv][khv][0]; LDA(dst, bufv, mhv) }
#define LDBF(dst, bufv, khv) { const bf16_t* BB_ = &Bs[bufv][khv][0]; \
    dst[0] = *(const v8bf*)&BB_[bofs]; \
    dst[1] = *(const v8bf*)&BB_[bofs + 512]; \
    dst[2] = *(const v8bf*)&BB_[bofs + 1024]; \
    dst[3] = *(const v8bf*)&BB_[bofs + 1536]; }

    v4f acc[8][4];
#pragma unroll
    for (int i = 0; i < 8; i++)
#pragma unroll
        for (int j = 0; j < 4; j++) acc[i][j] = (v4f){0.f, 0.f, 0.f, 0.f};

    v8bf aX[4], aY[4], bX[4], bY[4];

#define MF(AC, BC, M0) \
    __builtin_amdgcn_s_setprio(1); \
    acc[(M0)+0][0] = __builtin_amdgcn_mfma_f32_16x16x32_bf16(AC[0], BC[0], acc[(M0)+0][0], 0, 0, 0); \
    acc[(M0)+0][1] = __builtin_amdgcn_mfma_f32_16x16x32_bf16(AC[0], BC[1], acc[(M0)+0][1], 0, 0, 0); \
    acc[(M0)+0][2] = __builtin_amdgcn_mfma_f32_16x16x32_bf16(AC[0], BC[2], acc[(M0)+0][2], 0, 0, 0); \
    acc[(M0)+0][3] = __builtin_amdgcn_mfma_f32_16x16x32_bf16(AC[0], BC[3], acc[(M0)+0][3], 0, 0, 0); \
    acc[(M0)+1][0] = __builtin_amdgcn_mfma_f32_16x16x32_bf16(AC[1], BC[0], acc[(M0)+1][0], 0, 0, 0); \
    acc[(M0)+1][1] = __builtin_amdgcn_mfma_f32_16x16x32_bf16(AC[1], BC[1], acc[(M0)+1][1], 0, 0, 0); \
    acc[(M0)+1][2] = __builtin_amdgcn_mfma_f32_16x16x32_bf16(AC[1], BC[2], acc[(M0)+1][2], 0, 0, 0); \
    acc[(M0)+1][3] = __builtin_amdgcn_mfma_f32_16x16x32_bf16(AC[1], BC[3], acc[(M0)+1][3], 0, 0, 0); \
    acc[(M0)+2][0] = __builtin_amdgcn_mfma_f32_16x16x32_bf16(AC[2], BC[0], acc[(M0)+2][0], 0, 0, 0); \
    acc[(M0)+2][1] = __builtin_amdgcn_mfma_f32_16x16x32_bf16(AC[2], BC[1], acc[(M0)+2][1], 0, 0, 0); \
    acc[(M0)+2][2] = __builtin_amdgcn_mfma_f32_16x16x32_bf16(AC[2], BC[2], acc[(M0)+2][2], 0, 0, 0); \
    acc[(M0)+2][3] = __builtin_amdgcn_mfma_f32_16x16x32_bf16(AC[2], BC[3], acc[(M0)+2][3], 0, 0, 0); \
    acc[(M0)+3][0] = __builtin_amdgcn_mfma_f32_16x16x32_bf16(AC[3], BC[0], acc[(M0)+3][0], 0, 0, 0); \
    acc[(M0)+3][1] = __builtin_amdgcn_mfma_f32_16x16x32_bf16(AC[3], BC[1], acc[(M0)+3][1], 0, 0, 0); \
    acc[(M0)+3][2] = __builtin_amdgcn_mfma_f32_16x16x32_bf16(AC[3], BC[2], acc[(M0)+3][2], 0, 0, 0); \
    acc[(M0)+3][3] = __builtin_amdgcn_mfma_f32_16x16x32_bf16(AC[3], BC[3], acc[(M0)+3][3], 0, 0, 0); \
    __builtin_amdgcn_s_setprio(0);

#define TAIL_W6 { asm volatile("s_waitcnt vmcnt(6)" ::: "memory"); BAR; __builtin_amdgcn_sched_barrier(0); }
#define TAIL_W4 { asm volatile("s_waitcnt vmcnt(4)" ::: "memory"); BAR; __builtin_amdgcn_sched_barrier(0); }
#define TAIL_W0 { asm volatile("s_waitcnt vmcnt(0)" ::: "memory"); BAR; __builtin_amdgcn_sched_barrier(0); }
#define TAIL_B  { BAR; __builtin_amdgcn_sched_barrier(0); }

    // prologue: A/B(t0)kh0, A/B(t0)kh1, A/B(t1)kh0 (12 loads)
    STA(0, 0, 0); STB(0, 0, 0);
    STA(0, 1, 0); STB(0, 1, 0);
    STA(1, 0, 64); STB(1, 0, 64);
    asm volatile("s_waitcnt vmcnt(8)" ::: "memory");   // t0.kh0 landed
    BAR; __builtin_amdgcn_sched_barrier(0);
    LDAF(aX, 0, 0, 0); LDBF(bX, 0, 0);                 // frags for t0 P1

    // steady tile: P1(kh0,mh0) P2(kh0,mh1) P3(kh1,mh0) P4(kh1,mh1)
#define TILE(b, kc, S1, S2, S3, S4, T1, T3, P4B, P4LD) \
    S1; LDAF(aY, b, 0, 1);                    MF(aX, bX, 0); T1; \
    S2; LDBF(bY, b, 1); LDAF(aX, b, 1, 0);    MF(aY, bX, 4); TAIL_B; \
    S3; LDAF(aY, b, 1, 1);                    MF(aX, bY, 0); T3; \
    S4; if (P4LD) { LDBF(bX, P4B, 0); LDAF(aX, P4B, 0, 0); } \
                                              MF(aY, bY, 4); TAIL_B;

    int kb = 0;
#pragma unroll 1
    for (int tp = 0; tp < 7; ++tp, kb += 128) {
        // even tile (buf0): stages kh1(t+1)->buf1, kh0(t+2)->buf0
        TILE(0, kb, STA(1, 1, kb + 64), STB(1, 1, kb + 64),
                    STA(0, 0, kb + 128), STB(0, 0, kb + 128),
                    TAIL_W6, TAIL_W6, 1, 1)
        // odd tile (buf1)
        TILE(1, kb + 64, STA(0, 1, kb + 128), STB(0, 1, kb + 128),
                         STA(1, 0, kb + 192), STB(1, 0, kb + 192),
                         TAIL_W6, TAIL_W6, 0, 1)
    }
    // tile 14 (buf0, kb=896): stages only kh1(t15); P3 drain -> vmcnt(4)
    TILE(0, 896, STA(1, 1, 960), STB(1, 1, 960), , ,
                 TAIL_W6, TAIL_W4, 1, 1)
    // tile 15 (buf1): no stages; P1 tail vmcnt(0); no P4 loads
    { const int b = 1;
      LDAF(aY, b, 0, 1);                    MF(aX, bX, 0); TAIL_W0;
      LDBF(bY, b, 1); LDAF(aX, b, 1, 0);    MF(aY, bX, 4); TAIL_B;
      LDAF(aY, b, 1, 1);                    MF(aX, bY, 0); TAIL_B;
                                            MF(aY, bY, 4);
    }

#undef TILE
#undef MF
#undef TAIL_W6
#undef TAIL_W4
#undef TAIL_W0
#undef TAIL_B
#undef LDA
#undef LDAF
#undef LDBF
#undef STA
#undef STB

    // epilogue: acc[m][n] -> row m0 + wr*128 + m*16 + quad*4 + r,
    //                        col n0 + wc*64 + n*16 + ln
#pragma unroll
    for (int m = 0; m < 8; m++) {
#pragma unroll
        for (int r = 0; r < 4; r++) {
            int row = m0 + wr * 128 + m * 16 + quad * 4 + r;
#pragma unroll
            for (int n = 0; n < 4; n++) {
                int col = n0 + wc * 64 + n * 16 + ln;
                float v = acc[m][n][r] + bias[col];
                if (col < 1024) v *= qmul;
                C[(size_t)row * 3072 + col] = (bf16_t)v;
            }
        }
    }
}

// ---------------------------------------------------------------- GEMM  C = A * B^T (+bias) (+resid)
// (proj GEMM: N=1024; proven 128x128 3-buffer counted-vmcnt structure.)
__global__ __launch_bounds__(256, 3) void k_gemm_bt(
    const bf16_t* __restrict__ A, const bf16_t* __restrict__ Bm,
    const float* __restrict__ bias, const float* __restrict__ resid,
    bf16_t* __restrict__ Cb, float* __restrict__ Cf,
    int M, int N, int K, int qcols, float qmul)
{
    __shared__ bf16_t As[3][128 * 32];
    __shared__ bf16_t Bs[3][128 * 32];

    int nTile = N >> 7;
    int x = blockIdx.x & 7, g = blockIdx.x >> 3;
    int n_idx = g % nTile;
    int m_idx = (g / nTile) * 8 + x;
    int m0 = m_idx << 7;
    int n0 = n_idx << 7;
    int t = threadIdx.x;
    int w = t >> 6, lane = t & 63, quad = lane >> 4, ln = lane & 15;
    int wm = (w >> 1) << 6, wn = (w & 1) << 6;

    int srow = lane >> 2;                               // 0..15
    int scol = ((lane & 3) ^ ((lane >> 3) & 3)) << 3;   // swizzled logical chunk *8
    const bf16_t* Ag0 = A  + (size_t)(m0 + w * 16 +      srow) * K + scol;
    const bf16_t* Ag1 = A  + (size_t)(m0 + w * 16 + 64 + srow) * K + scol;
    const bf16_t* Bg0 = Bm + (size_t)(n0 + w * 16 +      srow) * K + scol;
    const bf16_t* Bg1 = Bm + (size_t)(n0 + w * 16 + 64 + srow) * K + scol;
    int lo0 = (w * 16) * 32, lo1 = (w * 16 + 64) * 32;

    v4f acc[4][4];
#pragma unroll
    for (int i = 0; i < 4; i++)
#pragma unroll
        for (int j = 0; j < 4; j++) acc[i][j] = (v4f){0.f, 0.f, 0.f, 0.f};

    bf16_t* aPrev = As[2]; bf16_t* aCur = As[0]; bf16_t* aNext = As[1];
    bf16_t* bPrev = Bs[2]; bf16_t* bCur = Bs[0]; bf16_t* bNext = Bs[1];

    GLD16(Ag0, aCur + lo0);
    GLD16(Ag1, aCur + lo1);
    GLD16(Bg0, bCur + lo0);
    GLD16(Bg1, bCur + lo1);
    GLD16(Ag0 + 32, aNext + lo0);
    GLD16(Ag1 + 32, aNext + lo1);
    GLD16(Bg0 + 32, bNext + lo0);
    GLD16(Bg1 + 32, bNext + lo1);

    int sw = (ln >> 1) & 3;   // read-side swizzle
    for (int k0 = 0; k0 < K; k0 += 32) {
        if (k0 + 32 < K) asm volatile("s_waitcnt vmcnt(4)" ::: "memory");
        else             asm volatile("s_waitcnt vmcnt(0)" ::: "memory");
        __builtin_amdgcn_s_barrier();
        __builtin_amdgcn_sched_barrier(0);
        if (k0 + 64 < K) {
            GLD16(Ag0 + k0 + 64, aPrev + lo0);
            GLD16(Ag1 + k0 + 64, aPrev + lo1);
            GLD16(Bg0 + k0 + 64, bPrev + lo0);
            GLD16(Bg1 + k0 + 64, bPrev + lo1);
        }
        v8bf af[4], bfr[4];
#pragma unroll
        for (int mt = 0; mt < 4; mt++)
            af[mt] = *(const v8bf*)&aCur[(wm + mt * 16 + ln) * 32 + ((quad ^ sw) << 3)];
#pragma unroll
        for (int nt = 0; nt < 4; nt++)
            bfr[nt] = *(const v8bf*)&bCur[(wn + nt * 16 + ln) * 32 + ((quad ^ sw) << 3)];
#pragma unroll
        for (int mt = 0; mt < 4; mt++)
#pragma unroll
            for (int nt = 0; nt < 4; nt++)
                acc[mt][nt] = __builtin_amdgcn_mfma_f32_16x16x32_bf16(af[mt], bfr[nt], acc[mt][nt], 0, 0, 0);
        bf16_t* ta = aPrev; aPrev = aCur; aCur = aNext; aNext = ta;
        bf16_t* tb = bPrev; bPrev = bCur; bCur = bNext; bNext = tb;
    }

#pragma unroll
    for (int mt = 0; mt < 4; mt++) {
#pragma unroll
        for (int r = 0; r < 4; r++) {
            int row = m0 + wm + mt * 16 + quad * 4 + r;
#pragma unroll
            for (int nt = 0; nt < 4; nt++) {
                int col = n0 + wn + nt * 16 + ln;
                float v = acc[mt][nt][r] + bias[col];
                if (Cf) Cf[(size_t)row * N + col] = v + resid[(size_t)row * N + col];
                else {
                    if (col < qcols) v *= qmul;
                    Cb[(size_t)row * N + col] = (bf16_t)v;
                }
            }
        }
    }
}

// ---------------------------------------------------------------- V transpose: qkv V-cols -> Vt[bh][d][s]
__global__ __launch_bounds__(256) void k_transpose_v(const bf16_t* __restrict__ qkv,
                                                     bf16_t* __restrict__ vt) {
    __shared__ bf16_t tile[64 * 72];
    int bid = blockIdx.x;
    int st = bid & 31, bh = bid >> 5, b = bh >> 4, h = bh & 15;
    int t = threadIdx.x;
    const bf16_t* src = qkv + (size_t)(b * SEQ + st * 64) * 3072 + 2048 + h * 64;
#pragma unroll
    for (int i = 0; i < 2; i++) {
        int c = t + i * 256, row = c >> 3, c8 = (c & 7) << 3;
        *(uint4*)&tile[row * 72 + c8] = *(const uint4*)(src + (size_t)row * 3072 + c8);
    }
    __syncthreads();
    bf16_t* dst = vt + (size_t)bh * DHEAD * SEQ + st * 64;
#pragma unroll
    for (int i = 0; i < 2; i++) {
        int c = t + i * 256, d = c >> 3, s8 = (c & 7) << 3;
        v8bf o;
#pragma unroll
        for (int j = 0; j < 8; j++) o[j] = tile[(s8 + j) * 72 + d];
        *(v8bf*)(dst + (size_t)d * SEQ + s8) = o;
    }
}

// ---------------------------------------------------------------- attention (register-resident P)
__global__ __launch_bounds__(256, 2) void k_attn(const bf16_t* __restrict__ qkv,
                                                 const bf16_t* __restrict__ vt,
                                                 bf16_t* __restrict__ attn) {
    __shared__ bf16_t Ks[2][64 * 64];
    __shared__ bf16_t Vs[2][64 * 64];

    int bid = blockIdx.x;
    int xcd = bid & 7, g = bid >> 3;
    int qt = g & 15;
    int bh = ((g >> 4) << 3) | xcd;
    int b = bh >> 4, h = bh & 15;
    int t = threadIdx.x, w = t >> 6, lane = t & 63, quad = lane >> 4, ln = lane & 15;
    int q0 = qt * 128 + w * 32;

    v8bf qf[2][2];
#pragma unroll
    for (int qs = 0; qs < 2; qs++) {
        const bf16_t* Qp = qkv + (size_t)(b * SEQ + q0 + qs * 16 + ln) * 3072 + h * 64 + quad * 8;
        qf[qs][0] = *(const v8bf*)Qp;
        qf[qs][1] = *(const v8bf*)(Qp + 32);
    }

    int srow = lane >> 3;                        // 0..7
    int scolK = ((lane & 7) ^ ((lane >> 3) & 3) ^ ((w & 1) << 2)) << 3;
    int scolV = ((lane & 7) ^ (lane >> 3)) << 3;
    const bf16_t* Kg0 = qkv + (size_t)(b * SEQ + w * 8 +      srow) * 3072 + 1024 + h * 64 + scolK;
    const bf16_t* Kg1 = qkv + (size_t)(b * SEQ + w * 8 + 32 + srow) * 3072 + 1024 + h * 64 + scolK;
    const bf16_t* Vg0 = vt + (size_t)bh * DHEAD * SEQ + (size_t)(w * 8 +      srow) * SEQ + scolV;
    const bf16_t* Vg1 = vt + (size_t)bh * DHEAD * SEQ + (size_t)(w * 8 + 32 + srow) * SEQ + scolV;
    int ko0 = (w * 8) * 64, ko1 = (w * 8 + 32) * 64;

    int gk = (ln & 3) | (((ln >> 2) & 1) << 2);
    int gv = ln & 7;
    int rrbase = ((ln >> 2) << 3) + (ln & 3);
    int o0 = (rrbase) * 64,       o1 = (rrbase + 4) * 64;
    int o2 = (rrbase + 32) * 64,  o3 = (rrbase + 36) * 64;

    const v4f z4 = (v4f){0.f, 0.f, 0.f, 0.f};
    v8bf ones8;
#pragma unroll
    for (int j = 0; j < 8; j++) ones8[j] = (bf16_t)1.0f;

    v4f o[2][4];
#pragma unroll
    for (int qs = 0; qs < 2; qs++)
#pragma unroll
        for (int d = 0; d < 4; d++) o[qs][d] = z4;
    v4f den[2] = {z4, z4};

    GLD16(Kg0, &Ks[0][ko0]);
    GLD16(Kg1, &Ks[0][ko1]);
    GLD16(Vg0, &Vs[0][ko0]);
    GLD16(Vg1, &Vs[0][ko1]);

    int buf = 0;
    for (int kt = 0; kt < SEQ; kt += 64, buf ^= 1) {
        __syncthreads();
        if (kt + 64 < SEQ) {
            GLD16(Kg0 + (size_t)(kt + 64) * 3072, &Ks[buf ^ 1][ko0]);
            GLD16(Kg1 + (size_t)(kt + 64) * 3072, &Ks[buf ^ 1][ko1]);
            GLD16(Vg0 + kt + 64, &Vs[buf ^ 1][ko0]);
            GLD16(Vg1 + kt + 64, &Vs[buf ^ 1][ko1]);
        }

        const bf16_t* Kb = &Ks[buf][0];
        v4f s0[4], s1[4];
        int rof[4] = {o0, o1, o2, o3};
#pragma unroll
        for (int nt = 0; nt < 4; nt++) {
            v8bf kf0 = *(const v8bf*)&Kb[rof[nt] + ((quad ^ gk) << 3)];
            v8bf kf1 = *(const v8bf*)&Kb[rof[nt] + (((quad | 4) ^ gk) << 3)];
            s0[nt] = __builtin_amdgcn_mfma_f32_16x16x32_bf16(kf0, qf[0][0], z4, 0, 0, 0);
            s0[nt] = __builtin_amdgcn_mfma_f32_16x16x32_bf16(kf1, qf[0][1], s0[nt], 0, 0, 0);
            s1[nt] = __builtin_amdgcn_mfma_f32_16x16x32_bf16(kf0, qf[1][0], z4, 0, 0, 0);
            s1[nt] = __builtin_amdgcn_mfma_f32_16x16x32_bf16(kf1, qf[1][1], s1[nt], 0, 0, 0);
        }

#pragma unroll
        for (int tk = 0; tk < 2; tk++) {
            v8bf vfd[4];
#pragma unroll
            for (int d = 0; d < 4; d++)
                vfd[d] = *(const v8bf*)&Vs[buf][(d * 16 + ln) * 64 + (((tk * 4 + quad) ^ gv) << 3)];
#pragma unroll
            for (int qs = 0; qs < 2; qs++) {
                v4f* s = qs ? s1 : s0;
                float e0 = __builtin_amdgcn_exp2f(s[2 * tk][0]);
                float e1 = __builtin_amdgcn_exp2f(s[2 * tk][1]);
                float e2 = __builtin_amdgcn_exp2f(s[2 * tk][2]);
                float e3 = __builtin_amdgcn_exp2f(s[2 * tk][3]);
                float e4 = __builtin_amdgcn_exp2f(s[2 * tk + 1][0]);
                float e5 = __builtin_amdgcn_exp2f(s[2 * tk + 1][1]);
                float e6 = __builtin_amdgcn_exp2f(s[2 * tk + 1][2]);
                float e7 = __builtin_amdgcn_exp2f(s[2 * tk + 1][3]);
                v8bf pf;
                pf[0] = (bf16_t)e0; pf[1] = (bf16_t)e1; pf[2] = (bf16_t)e2; pf[3] = (bf16_t)e3;
                pf[4] = (bf16_t)e4; pf[5] = (bf16_t)e5; pf[6] = (bf16_t)e6; pf[7] = (bf16_t)e7;
                den[qs] = __builtin_amdgcn_mfma_f32_16x16x32_bf16(pf, ones8, den[qs], 0, 0, 0);
#pragma unroll
                for (int d = 0; d < 4; d++)
                    o[qs][d] = __builtin_amdgcn_mfma_f32_16x16x32_bf16(pf, vfd[d], o[qs][d], 0, 0, 0);
            }
        }
    }

#pragma unroll
    for (int qs = 0; qs < 2; qs++) {
        int rowg = b * SEQ + q0 + qs * 16;
#pragma unroll
        for (int r = 0; r < 4; r++) {
            float inv = 1.f / den[qs][r];
#pragma unroll
            for (int d = 0; d < 4; d++)
                attn[(size_t)(rowg + quad * 4 + r) * D_MODEL + h * 64 + d * 16 + ln] =
                    (bf16_t)(o[qs][d][r] * inv);
        }
    }
}

// ---------------------------------------------------------------- LayerNorm (one row / block)
__global__ __launch_bounds__(256) void k_layernorm(const float* __restrict__ y,
                                                   const float* __restrict__ g,
                                                   const float* __restrict__ beta,
                                                   float* __restrict__ out) {
    __shared__ float rs[4], rq[4];
    int row = blockIdx.x, t = threadIdx.x;
    int w = t >> 6, lane = t & 63;
    float4 v = ((const float4*)(y + (size_t)row * D_MODEL))[t];
    float s = v.x + v.y + v.z + v.w;
    float q = v.x * v.x + v.y * v.y + v.z * v.z + v.w * v.w;
#pragma unroll
    for (int off = 1; off < 64; off <<= 1) {
        s += __shfl_xor(s, off);
        q += __shfl_xor(q, off);
    }
    if (lane == 0) { rs[w] = s; rq[w] = q; }
    __syncthreads();
    s = rs[0] + rs[1] + rs[2] + rs[3];
    q = rq[0] + rq[1] + rq[2] + rq[3];
    float mu = s * (1.f / D_MODEL);
    float var = q * (1.f / D_MODEL) - mu * mu;
    float rstd = rsqrtf(var + 1e-5f);
    float4 gg = ((const float4*)g)[t];
    float4 bb = ((const float4*)beta)[t];
    float4 o;
    o.x = (v.x - mu) * rstd * gg.x + bb.x;
    o.y = (v.y - mu) * rstd * gg.y + bb.y;
    o.z = (v.z - mu) * rstd * gg.z + bb.z;
    o.w = (v.w - mu) * rstd * gg.w + bb.w;
    ((float4*)(out + (size_t)row * D_MODEL))[t] = o;
}

// ---------------------------------------------------------------- launch
extern "C" void kernel_launch(void* const* d_in, const int* in_sizes, int n_in,
                              void* d_out, int out_size, void* d_ws, size_t ws_size,
                              hipStream_t stream) {
    const float* batch = (const float*)d_in[0];
    const float* wq = (const float*)d_in[1];
    const float* bq = (const float*)d_in[2];
    const float* wk = (const float*)d_in[3];
    const float* bk = (const float*)d_in[4];
    const float* wv = (const float*)d_in[5];
    const float* bv = (const float*)d_in[6];
    const float* wo = (const float*)d_in[7];
    const float* bo = (const float*)d_in[8];
    const float* ln_g = (const float*)d_in[9];
    const float* ln_b = (const float*)d_in[10];
    float* out = (float*)d_out;

    char* ws = (char*)d_ws;
    size_t offXb   = 0;                                          // bf16 X (later Vt)
    size_t offWqkv = offXb + (size_t)ROWS * D_MODEL * 2;
    size_t offWo   = offWqkv + (size_t)3072 * 1024 * 2;
    size_t offBias = offWo + (size_t)1024 * 1024 * 2;
    size_t offQKV  = offBias + 3072 * 4;                         // bf16 qkv (later fp32 y)
    size_t offAttn = offQKV + (size_t)ROWS * 3072 * 2;
    size_t total   = offAttn + (size_t)ROWS * D_MODEL * 2;       // = 92,286,976
    if (ws_size < total) return;

    bf16_t* Xb   = (bf16_t*)(ws + offXb);
    bf16_t* Vt   = (bf16_t*)(ws + offXb);
    bf16_t* Wqkv = (bf16_t*)(ws + offWqkv);
    bf16_t* Wob  = (bf16_t*)(ws + offWo);
    float*  bqkv = (float*)(ws + offBias);
    bf16_t* qkv  = (bf16_t*)(ws + offQKV);
    float*  y    = (float*)(ws + offQKV);
    bf16_t* attn = (bf16_t*)(ws + offAttn);

    const float SC = 0.125f * 1.44269504088896f;  // 1/sqrt(64) * log2(e), folded into Q

    k_prep<<<12300, 256, 0, stream>>>(batch, wq, wk, wv, wo, bq, bk, bv,
                                      Xb, Wqkv, Wob, bqkv);
    k_gemm256<<<384, 512, 0, stream>>>(Xb, Wqkv, bqkv, qkv, SC);
    k_transpose_v<<<2048, 256, 0, stream>>>(qkv, Vt);
    k_attn<<<1024, 256, 0, stream>>>(qkv, Vt, attn);
    k_gemm_bt<<<64 * 8, 256, 0, stream>>>(attn, Wob, bo, batch, nullptr, y,
                                          8192, 1024, 1024, 0, 1.0f);
    k_layernorm<<<8192, 256, 0, stream>>>(y, ln_g, ln_b, out);
}

// Round 7
// 296.666 us; speedup vs baseline: 1.0442x; 1.0254x over previous
//
#include <hip/hip_runtime.h>

typedef __bf16 bf16_t;
typedef __bf16 v8bf __attribute__((ext_vector_type(8)));
typedef __bf16 v4bf __attribute__((ext_vector_type(4)));
typedef float  v4f  __attribute__((ext_vector_type(4)));

#define D_MODEL 1024
#define NHEAD   16
#define DHEAD   64
#define SEQ     2048
#define BATCH   4
#define ROWS    (BATCH*SEQ)   // 8192

// async global->LDS, 16B per lane; LDS dest MUST be wave-uniform:
// HW writes base + lane*16 (guide §5: not a per-lane scatter).
#define GLD16(g, l) __builtin_amdgcn_global_load_lds( \
    (const __attribute__((address_space(1))) void*)(g), \
    (__attribute__((address_space(3))) void*)(l), 16, 0, 0)

#define BAR asm volatile("s_barrier" ::: "memory")

// ---------------------------------------------------------------- fused prep (casts + bias pack)
// R7: grid-stride at 2048 blocks (was 12300 one-shot micro-blocks).
__global__ __launch_bounds__(256) void k_prep(const float* __restrict__ batch,
                                              const float* __restrict__ wq,
                                              const float* __restrict__ wk,
                                              const float* __restrict__ wv,
                                              const float* __restrict__ wo,
                                              const float* __restrict__ bq,
                                              const float* __restrict__ bk,
                                              const float* __restrict__ bv,
                                              bf16_t* __restrict__ Xb,
                                              bf16_t* __restrict__ Wqkv,
                                              bf16_t* __restrict__ Wob,
                                              float* __restrict__ bqkv) {
    int t = threadIdx.x;
    for (int bid = blockIdx.x; bid < 12300; bid += 2048) {
        const float* src; bf16_t* dst; int idx;
        if (bid < 8192)       { src = batch; dst = Xb;             idx = bid * 256 + t; }
        else if (bid < 9216)  { src = wq;    dst = Wqkv;           idx = (bid - 8192) * 256 + t; }
        else if (bid < 10240) { src = wk;    dst = Wqkv + 1048576; idx = (bid - 9216) * 256 + t; }
        else if (bid < 11264) { src = wv;    dst = Wqkv + 2097152; idx = (bid - 10240) * 256 + t; }
        else if (bid < 12288) { src = wo;    dst = Wob;            idx = (bid - 11264) * 256 + t; }
        else {
            int i = (bid - 12288) * 256 + t;   // 0..3071
            if (i < 1024) bqkv[i] = bq[i];
            else if (i < 2048) bqkv[i] = bk[i - 1024];
            else if (i < 3072) bqkv[i] = bv[i - 2048];
            continue;
        }
        float4 f = ((const float4*)src)[idx];
        v4bf o;
        o[0] = (bf16_t)f.x; o[1] = (bf16_t)f.y; o[2] = (bf16_t)f.z; o[3] = (bf16_t)f.w;
        ((v4bf*)dst)[idx] = o;
    }
}

// ---------------------------------------------------------------- 256x256 pipelined 4-phase GEMM (QKV)
// C = A * B^T (+bias, qmul on first 1024 cols). M=8192 N=3072 K=1024 HARDCODED.
// BM=BN=256, BK=64 (2 K-halves of 32), 512 thr = 8 waves, acc[8][4].
// LDS 128 KiB: As/Bs[2 tile-buf][2 K-half][256x32].
// Swizzle g(row)=(row>>1)&3 both sides (conflict-free, verified R6: 0).
// Fragment reads pipelined one phase ahead; one barrier/phase; counted
// vmcnt drains at P1/P3 (ledger verified R6). Unchanged this round.
__global__ __launch_bounds__(512, 2) void k_gemm256(
    const bf16_t* __restrict__ A, const bf16_t* __restrict__ Bm,
    const float* __restrict__ bias, bf16_t* __restrict__ C, float qmul)
{
    __shared__ bf16_t As[2][2][256 * 32];
    __shared__ bf16_t Bs[2][2][256 * 32];

    const int K = 1024;
    int bid = blockIdx.x;
    int wg = (bid & 7) * 48 + (bid >> 3);      // XCD-chunked: 384 = 8 x 48
    int m_idx = wg / 12, n_idx = wg % 12;
    int m0 = m_idx << 8, n0 = n_idx << 8;

    int t = threadIdx.x;
    int lane = t & 63, quad = lane >> 4, ln = lane & 15;
    int w = t >> 6, wr = w >> 2, wc = w & 3;

    int cl = (t & 3) ^ ((t >> 3) & 3);
    const bf16_t* Ag = A  + (size_t)(m0 + (t >> 2)) * K + cl * 8;
    const bf16_t* Bg = Bm + (size_t)(n0 + (t >> 2)) * K + cl * 8;
    int wb = w << 9;                            // wave-uniform LDS base

#define STA(bufv, khv, kc) { const bf16_t* g_ = Ag + (kc) + ((khv) << 5); \
    GLD16(g_, &As[bufv][khv][wb]); GLD16(g_ + 131072, &As[bufv][khv][wb + 4096]); }
#define STB(bufv, khv, kc) { const bf16_t* g_ = Bg + (kc) + ((khv) << 5); \
    GLD16(g_, &Bs[bufv][khv][wb]); GLD16(g_ + 131072, &Bs[bufv][khv][wb + 4096]); }

    int rsw = (quad ^ ((ln >> 1) & 3)) << 3;
    int aofs = (wr * 128 + ln) * 32 + rsw;
    int bofs = (wc * 64 + ln) * 32 + rsw;

#define LDA(dst, bufv, mhv) { \
    dst[0] = *(const v8bf*)&AB_[aofs + (mhv) * 2048]; \
    dst[1] = *(const v8bf*)&AB_[aofs + (mhv) * 2048 + 512]; \
    dst[2] = *(const v8bf*)&AB_[aofs + (mhv) * 2048 + 1024]; \
    dst[3] = *(const v8bf*)&AB_[aofs + (mhv) * 2048 + 1536]; }
#define LDAF(dst, bufv, khv, mhv) { const bf16_t* AB_ = &As[bufv][khv][0]; LDA(dst, bufv, mhv) }
#define LDBF(dst, bufv, khv) { const bf16_t* BB_ = &Bs[bufv][khv][0]; \
    dst[0] = *(const v8bf*)&BB_[bofs]; \
    dst[1] = *(const v8bf*)&BB_[bofs + 512]; \
    dst[2] = *(const v8bf*)&BB_[bofs + 1024]; \
    dst[3] = *(const v8bf*)&BB_[bofs + 1536]; }

    v4f acc[8][4];
#pragma unroll
    for (int i = 0; i < 8; i++)
#pragma unroll
        for (int j = 0; j < 4; j++) acc[i][j] = (v4f){0.f, 0.f, 0.f, 0.f};

    v8bf aX[4], aY[4], bX[4], bY[4];

#define MF(AC, BC, M0) \
    __builtin_amdgcn_s_setprio(1); \
    acc[(M0)+0][0] = __builtin_amdgcn_mfma_f32_16x16x32_bf16(AC[0], BC[0], acc[(M0)+0][0], 0, 0, 0); \
    acc[(M0)+0][1] = __builtin_amdgcn_mfma_f32_16x16x32_bf16(AC[0], BC[1], acc[(M0)+0][1], 0, 0, 0); \
    acc[(M0)+0][2] = __builtin_amdgcn_mfma_f32_16x16x32_bf16(AC[0], BC[2], acc[(M0)+0][2], 0, 0, 0); \
    acc[(M0)+0][3] = __builtin_amdgcn_mfma_f32_16x16x32_bf16(AC[0], BC[3], acc[(M0)+0][3], 0, 0, 0); \
    acc[(M0)+1][0] = __builtin_amdgcn_mfma_f32_16x16x32_bf16(AC[1], BC[0], acc[(M0)+1][0], 0, 0, 0); \
    acc[(M0)+1][1] = __builtin_amdgcn_mfma_f32_16x16x32_bf16(AC[1], BC[1], acc[(M0)+1][1], 0, 0, 0); \
    acc[(M0)+1][2] = __builtin_amdgcn_mfma_f32_16x16x32_bf16(AC[1], BC[2], acc[(M0)+1][2], 0, 0, 0); \
    acc[(M0)+1][3] = __builtin_amdgcn_mfma_f32_16x16x32_bf16(AC[1], BC[3], acc[(M0)+1][3], 0, 0, 0); \
    acc[(M0)+2][0] = __builtin_amdgcn_mfma_f32_16x16x32_bf16(AC[2], BC[0], acc[(M0)+2][0], 0, 0, 0); \
    acc[(M0)+2][1] = __builtin_amdgcn_mfma_f32_16x16x32_bf16(AC[2], BC[1], acc[(M0)+2][1], 0, 0, 0); \
    acc[(M0)+2][2] = __builtin_amdgcn_mfma_f32_16x16x32_bf16(AC[2], BC[2], acc[(M0)+2][2], 0, 0, 0); \
    acc[(M0)+2][3] = __builtin_amdgcn_mfma_f32_16x16x32_bf16(AC[2], BC[3], acc[(M0)+2][3], 0, 0, 0); \
    acc[(M0)+3][0] = __builtin_amdgcn_mfma_f32_16x16x32_bf16(AC[3], BC[0], acc[(M0)+3][0], 0, 0, 0); \
    acc[(M0)+3][1] = __builtin_amdgcn_mfma_f32_16x16x32_bf16(AC[3], BC[1], acc[(M0)+3][1], 0, 0, 0); \
    acc[(M0)+3][2] = __builtin_amdgcn_mfma_f32_16x16x32_bf16(AC[3], BC[2], acc[(M0)+3][2], 0, 0, 0); \
    acc[(M0)+3][3] = __builtin_amdgcn_mfma_f32_16x16x32_bf16(AC[3], BC[3], acc[(M0)+3][3], 0, 0, 0); \
    __builtin_amdgcn_s_setprio(0);

#define TAIL_W6 { asm volatile("s_waitcnt vmcnt(6)" ::: "memory"); BAR; __builtin_amdgcn_sched_barrier(0); }
#define TAIL_W4 { asm volatile("s_waitcnt vmcnt(4)" ::: "memory"); BAR; __builtin_amdgcn_sched_barrier(0); }
#define TAIL_W0 { asm volatile("s_waitcnt vmcnt(0)" ::: "memory"); BAR; __builtin_amdgcn_sched_barrier(0); }
#define TAIL_B  { BAR; __builtin_amdgcn_sched_barrier(0); }

    // prologue: A/B(t0)kh0, A/B(t0)kh1, A/B(t1)kh0 (12 loads)
    STA(0, 0, 0); STB(0, 0, 0);
    STA(0, 1, 0); STB(0, 1, 0);
    STA(1, 0, 64); STB(1, 0, 64);
    asm volatile("s_waitcnt vmcnt(8)" ::: "memory");   // t0.kh0 landed
    BAR; __builtin_amdgcn_sched_barrier(0);
    LDAF(aX, 0, 0, 0); LDBF(bX, 0, 0);                 // frags for t0 P1

#define TILE(b, kc, S1, S2, S3, S4, T1, T3, P4B, P4LD) \
    S1; LDAF(aY, b, 0, 1);                    MF(aX, bX, 0); T1; \
    S2; LDBF(bY, b, 1); LDAF(aX, b, 1, 0);    MF(aY, bX, 4); TAIL_B; \
    S3; LDAF(aY, b, 1, 1);                    MF(aX, bY, 0); T3; \
    S4; if (P4LD) { LDBF(bX, P4B, 0); LDAF(aX, P4B, 0, 0); } \
                                              MF(aY, bY, 4); TAIL_B;

    int kb = 0;
#pragma unroll 1
    for (int tp = 0; tp < 7; ++tp, kb += 128) {
        TILE(0, kb, STA(1, 1, kb + 64), STB(1, 1, kb + 64),
                    STA(0, 0, kb + 128), STB(0, 0, kb + 128),
                    TAIL_W6, TAIL_W6, 1, 1)
        TILE(1, kb + 64, STA(0, 1, kb + 128), STB(0, 1, kb + 128),
                         STA(1, 0, kb + 192), STB(1, 0, kb + 192),
                         TAIL_W6, TAIL_W6, 0, 1)
    }
    TILE(0, 896, STA(1, 1, 960), STB(1, 1, 960), , ,
                 TAIL_W6, TAIL_W4, 1, 1)
    { const int b = 1;
      LDAF(aY, b, 0, 1);                    MF(aX, bX, 0); TAIL_W0;
      LDBF(bY, b, 1); LDAF(aX, b, 1, 0);    MF(aY, bX, 4); TAIL_B;
      LDAF(aY, b, 1, 1);                    MF(aX, bY, 0); TAIL_B;
                                            MF(aY, bY, 4);
    }

#undef TILE
#undef MF
#undef TAIL_W6
#undef TAIL_W4
#undef TAIL_W0
#undef TAIL_B
#undef LDA
#undef LDAF
#undef LDBF
#undef STA
#undef STB

#pragma unroll
    for (int m = 0; m < 8; m++) {
#pragma unroll
        for (int r = 0; r < 4; r++) {
            int row = m0 + wr * 128 + m * 16 + quad * 4 + r;
#pragma unroll
            for (int n = 0; n < 4; n++) {
                int col = n0 + wc * 64 + n * 16 + ln;
                float v = acc[m][n][r] + bias[col];
                if (col < 1024) v *= qmul;
                C[(size_t)row * 3072 + col] = (bf16_t)v;
            }
        }
    }
}

// ---------------------------------------------------------------- GEMM  C = A * B^T (+bias) (+resid)
// (proj GEMM: N=1024; proven 128x128 3-buffer counted-vmcnt structure.)
__global__ __launch_bounds__(256, 3) void k_gemm_bt(
    const bf16_t* __restrict__ A, const bf16_t* __restrict__ Bm,
    const float* __restrict__ bias, const float* __restrict__ resid,
    bf16_t* __restrict__ Cb, float* __restrict__ Cf,
    int M, int N, int K, int qcols, float qmul)
{
    __shared__ bf16_t As[3][128 * 32];
    __shared__ bf16_t Bs[3][128 * 32];

    int nTile = N >> 7;
    int x = blockIdx.x & 7, g = blockIdx.x >> 3;
    int n_idx = g % nTile;
    int m_idx = (g / nTile) * 8 + x;
    int m0 = m_idx << 7;
    int n0 = n_idx << 7;
    int t = threadIdx.x;
    int w = t >> 6, lane = t & 63, quad = lane >> 4, ln = lane & 15;
    int wm = (w >> 1) << 6, wn = (w & 1) << 6;

    int srow = lane >> 2;                               // 0..15
    int scol = ((lane & 3) ^ ((lane >> 3) & 3)) << 3;   // swizzled logical chunk *8
    const bf16_t* Ag0 = A  + (size_t)(m0 + w * 16 +      srow) * K + scol;
    const bf16_t* Ag1 = A  + (size_t)(m0 + w * 16 + 64 + srow) * K + scol;
    const bf16_t* Bg0 = Bm + (size_t)(n0 + w * 16 +      srow) * K + scol;
    const bf16_t* Bg1 = Bm + (size_t)(n0 + w * 16 + 64 + srow) * K + scol;
    int lo0 = (w * 16) * 32, lo1 = (w * 16 + 64) * 32;

    v4f acc[4][4];
#pragma unroll
    for (int i = 0; i < 4; i++)
#pragma unroll
        for (int j = 0; j < 4; j++) acc[i][j] = (v4f){0.f, 0.f, 0.f, 0.f};

    bf16_t* aPrev = As[2]; bf16_t* aCur = As[0]; bf16_t* aNext = As[1];
    bf16_t* bPrev = Bs[2]; bf16_t* bCur = Bs[0]; bf16_t* bNext = Bs[1];

    GLD16(Ag0, aCur + lo0);
    GLD16(Ag1, aCur + lo1);
    GLD16(Bg0, bCur + lo0);
    GLD16(Bg1, bCur + lo1);
    GLD16(Ag0 + 32, aNext + lo0);
    GLD16(Ag1 + 32, aNext + lo1);
    GLD16(Bg0 + 32, bNext + lo0);
    GLD16(Bg1 + 32, bNext + lo1);

    int sw = (ln >> 1) & 3;   // read-side swizzle
    for (int k0 = 0; k0 < K; k0 += 32) {
        if (k0 + 32 < K) asm volatile("s_waitcnt vmcnt(4)" ::: "memory");
        else             asm volatile("s_waitcnt vmcnt(0)" ::: "memory");
        __builtin_amdgcn_s_barrier();
        __builtin_amdgcn_sched_barrier(0);
        if (k0 + 64 < K) {
            GLD16(Ag0 + k0 + 64, aPrev + lo0);
            GLD16(Ag1 + k0 + 64, aPrev + lo1);
            GLD16(Bg0 + k0 + 64, bPrev + lo0);
            GLD16(Bg1 + k0 + 64, bPrev + lo1);
        }
        v8bf af[4], bfr[4];
#pragma unroll
        for (int mt = 0; mt < 4; mt++)
            af[mt] = *(const v8bf*)&aCur[(wm + mt * 16 + ln) * 32 + ((quad ^ sw) << 3)];
#pragma unroll
        for (int nt = 0; nt < 4; nt++)
            bfr[nt] = *(const v8bf*)&bCur[(wn + nt * 16 + ln) * 32 + ((quad ^ sw) << 3)];
#pragma unroll
        for (int mt = 0; mt < 4; mt++)
#pragma unroll
            for (int nt = 0; nt < 4; nt++)
                acc[mt][nt] = __builtin_amdgcn_mfma_f32_16x16x32_bf16(af[mt], bfr[nt], acc[mt][nt], 0, 0, 0);
        bf16_t* ta = aPrev; aPrev = aCur; aCur = aNext; aNext = ta;
        bf16_t* tb = bPrev; bPrev = bCur; bCur = bNext; bNext = tb;
    }

#pragma unroll
    for (int mt = 0; mt < 4; mt++) {
#pragma unroll
        for (int r = 0; r < 4; r++) {
            int row = m0 + wm + mt * 16 + quad * 4 + r;
#pragma unroll
            for (int nt = 0; nt < 4; nt++) {
                int col = n0 + wn + nt * 16 + ln;
                float v = acc[mt][nt][r] + bias[col];
                if (Cf) Cf[(size_t)row * N + col] = v + resid[(size_t)row * N + col];
                else {
                    if (col < qcols) v *= qmul;
                    Cb[(size_t)row * N + col] = (bf16_t)v;
                }
            }
        }
    }
}

// ---------------------------------------------------------------- V transpose: qkv V-cols -> Vt[bh][d][s]
__global__ __launch_bounds__(256) void k_transpose_v(const bf16_t* __restrict__ qkv,
                                                     bf16_t* __restrict__ vt) {
    __shared__ bf16_t tile[64 * 72];
    int bid = blockIdx.x;
    int st = bid & 31, bh = bid >> 5, b = bh >> 4, h = bh & 15;
    int t = threadIdx.x;
    const bf16_t* src = qkv + (size_t)(b * SEQ + st * 64) * 3072 + 2048 + h * 64;
#pragma unroll
    for (int i = 0; i < 2; i++) {
        int c = t + i * 256, row = c >> 3, c8 = (c & 7) << 3;
        *(uint4*)&tile[row * 72 + c8] = *(const uint4*)(src + (size_t)row * 3072 + c8);
    }
    __syncthreads();
    bf16_t* dst = vt + (size_t)bh * DHEAD * SEQ + st * 64;
#pragma unroll
    for (int i = 0; i < 2; i++) {
        int c = t + i * 256, d = c >> 3, s8 = (c & 7) << 3;
        v8bf o;
#pragma unroll
        for (int j = 0; j < 8; j++) o[j] = tile[(s8 + j) * 72 + d];
        *(v8bf*)(dst + (size_t)d * SEQ + s8) = o;
    }
}

// ---------------------------------------------------------------- attention (register-resident P)
// R7: __launch_bounds__(256, 4) -> request 4 blocks/CU residency (grid
// 1024 = exactly 4/CU, one balanced round). LDS 32KB x 4 = 128KB OK,
// VGPR 64 OK. R6 measured Occupancy 31% (~2.5 blocks) at (256,2) with
// 92% combined MFMA+VALU issue -- more co-resident waves = better
// cross-wave pipe interleave (m114 mechanism).
__global__ __launch_bounds__(256, 4) void k_attn(const bf16_t* __restrict__ qkv,
                                                 const bf16_t* __restrict__ vt,
                                                 bf16_t* __restrict__ attn) {
    __shared__ bf16_t Ks[2][64 * 64];
    __shared__ bf16_t Vs[2][64 * 64];

    int bid = blockIdx.x;
    int xcd = bid & 7, g = bid >> 3;
    int qt = g & 15;
    int bh = ((g >> 4) << 3) | xcd;
    int b = bh >> 4, h = bh & 15;
    int t = threadIdx.x, w = t >> 6, lane = t & 63, quad = lane >> 4, ln = lane & 15;
    int q0 = qt * 128 + w * 32;

    v8bf qf[2][2];
#pragma unroll
    for (int qs = 0; qs < 2; qs++) {
        const bf16_t* Qp = qkv + (size_t)(b * SEQ + q0 + qs * 16 + ln) * 3072 + h * 64 + quad * 8;
        qf[qs][0] = *(const v8bf*)Qp;
        qf[qs][1] = *(const v8bf*)(Qp + 32);
    }

    int srow = lane >> 3;                        // 0..7
    int scolK = ((lane & 7) ^ ((lane >> 3) & 3) ^ ((w & 1) << 2)) << 3;
    int scolV = ((lane & 7) ^ (lane >> 3)) << 3;
    const bf16_t* Kg0 = qkv + (size_t)(b * SEQ + w * 8 +      srow) * 3072 + 1024 + h * 64 + scolK;
    const bf16_t* Kg1 = qkv + (size_t)(b * SEQ + w * 8 + 32 + srow) * 3072 + 1024 + h * 64 + scolK;
    const bf16_t* Vg0 = vt + (size_t)bh * DHEAD * SEQ + (size_t)(w * 8 +      srow) * SEQ + scolV;
    const bf16_t* Vg1 = vt + (size_t)bh * DHEAD * SEQ + (size_t)(w * 8 + 32 + srow) * SEQ + scolV;
    int ko0 = (w * 8) * 64, ko1 = (w * 8 + 32) * 64;

    int gk = (ln & 3) | (((ln >> 2) & 1) << 2);
    int gv = ln & 7;
    int rrbase = ((ln >> 2) << 3) + (ln & 3);
    int o0 = (rrbase) * 64,       o1 = (rrbase + 4) * 64;
    int o2 = (rrbase + 32) * 64,  o3 = (rrbase + 36) * 64;

    const v4f z4 = (v4f){0.f, 0.f, 0.f, 0.f};
    v8bf ones8;
#pragma unroll
    for (int j = 0; j < 8; j++) ones8[j] = (bf16_t)1.0f;

    v4f o[2][4];
#pragma unroll
    for (int qs = 0; qs < 2; qs++)
#pragma unroll
        for (int d = 0; d < 4; d++) o[qs][d] = z4;
    v4f den[2] = {z4, z4};

    GLD16(Kg0, &Ks[0][ko0]);
    GLD16(Kg1, &Ks[0][ko1]);
    GLD16(Vg0, &Vs[0][ko0]);
    GLD16(Vg1, &Vs[0][ko1]);

    int buf = 0;
    for (int kt = 0; kt < SEQ; kt += 64, buf ^= 1) {
        __syncthreads();
        if (kt + 64 < SEQ) {
            GLD16(Kg0 + (size_t)(kt + 64) * 3072, &Ks[buf ^ 1][ko0]);
            GLD16(Kg1 + (size_t)(kt + 64) * 3072, &Ks[buf ^ 1][ko1]);
            GLD16(Vg0 + kt + 64, &Vs[buf ^ 1][ko0]);
            GLD16(Vg1 + kt + 64, &Vs[buf ^ 1][ko1]);
        }

        const bf16_t* Kb = &Ks[buf][0];
        v4f s0[4], s1[4];
        int rof[4] = {o0, o1, o2, o3};
#pragma unroll
        for (int nt = 0; nt < 4; nt++) {
            v8bf kf0 = *(const v8bf*)&Kb[rof[nt] + ((quad ^ gk) << 3)];
            v8bf kf1 = *(const v8bf*)&Kb[rof[nt] + (((quad | 4) ^ gk) << 3)];
            s0[nt] = __builtin_amdgcn_mfma_f32_16x16x32_bf16(kf0, qf[0][0], z4, 0, 0, 0);
            s0[nt] = __builtin_amdgcn_mfma_f32_16x16x32_bf16(kf1, qf[0][1], s0[nt], 0, 0, 0);
            s1[nt] = __builtin_amdgcn_mfma_f32_16x16x32_bf16(kf0, qf[1][0], z4, 0, 0, 0);
            s1[nt] = __builtin_amdgcn_mfma_f32_16x16x32_bf16(kf1, qf[1][1], s1[nt], 0, 0, 0);
        }

#pragma unroll
        for (int tk = 0; tk < 2; tk++) {
            v8bf vfd[4];
#pragma unroll
            for (int d = 0; d < 4; d++)
                vfd[d] = *(const v8bf*)&Vs[buf][(d * 16 + ln) * 64 + (((tk * 4 + quad) ^ gv) << 3)];
#pragma unroll
            for (int qs = 0; qs < 2; qs++) {
                v4f* s = qs ? s1 : s0;
                float e0 = __builtin_amdgcn_exp2f(s[2 * tk][0]);
                float e1 = __builtin_amdgcn_exp2f(s[2 * tk][1]);
                float e2 = __builtin_amdgcn_exp2f(s[2 * tk][2]);
                float e3 = __builtin_amdgcn_exp2f(s[2 * tk][3]);
                float e4 = __builtin_amdgcn_exp2f(s[2 * tk + 1][0]);
                float e5 = __builtin_amdgcn_exp2f(s[2 * tk + 1][1]);
                float e6 = __builtin_amdgcn_exp2f(s[2 * tk + 1][2]);
                float e7 = __builtin_amdgcn_exp2f(s[2 * tk + 1][3]);
                v8bf pf;
                pf[0] = (bf16_t)e0; pf[1] = (bf16_t)e1; pf[2] = (bf16_t)e2; pf[3] = (bf16_t)e3;
                pf[4] = (bf16_t)e4; pf[5] = (bf16_t)e5; pf[6] = (bf16_t)e6; pf[7] = (bf16_t)e7;
                den[qs] = __builtin_amdgcn_mfma_f32_16x16x32_bf16(pf, ones8, den[qs], 0, 0, 0);
#pragma unroll
                for (int d = 0; d < 4; d++)
                    o[qs][d] = __builtin_amdgcn_mfma_f32_16x16x32_bf16(pf, vfd[d], o[qs][d], 0, 0, 0);
            }
        }
    }

#pragma unroll
    for (int qs = 0; qs < 2; qs++) {
        int rowg = b * SEQ + q0 + qs * 16;
#pragma unroll
        for (int r = 0; r < 4; r++) {
            float inv = 1.f / den[qs][r];
#pragma unroll
            for (int d = 0; d < 4; d++)
                attn[(size_t)(rowg + quad * 4 + r) * D_MODEL + h * 64 + d * 16 + ln] =
                    (bf16_t)(o[qs][d][r] * inv);
        }
    }
}

// ---------------------------------------------------------------- LayerNorm (one row / block)
__global__ __launch_bounds__(256) void k_layernorm(const float* __restrict__ y,
                                                   const float* __restrict__ g,
                                                   const float* __restrict__ beta,
                                                   float* __restrict__ out) {
    __shared__ float rs[4], rq[4];
    int row = blockIdx.x, t = threadIdx.x;
    int w = t >> 6, lane = t & 63;
    float4 v = ((const float4*)(y + (size_t)row * D_MODEL))[t];
    float s = v.x + v.y + v.z + v.w;
    float q = v.x * v.x + v.y * v.y + v.z * v.z + v.w * v.w;
#pragma unroll
    for (int off = 1; off < 64; off <<= 1) {
        s += __shfl_xor(s, off);
        q += __shfl_xor(q, off);
    }
    if (lane == 0) { rs[w] = s; rq[w] = q; }
    __syncthreads();
    s = rs[0] + rs[1] + rs[2] + rs[3];
    q = rq[0] + rq[1] + rq[2] + rq[3];
    float mu = s * (1.f / D_MODEL);
    float var = q * (1.f / D_MODEL) - mu * mu;
    float rstd = rsqrtf(var + 1e-5f);
    float4 gg = ((const float4*)g)[t];
    float4 bb = ((const float4*)beta)[t];
    float4 o;
    o.x = (v.x - mu) * rstd * gg.x + bb.x;
    o.y = (v.y - mu) * rstd * gg.y + bb.y;
    o.z = (v.z - mu) * rstd * gg.z + bb.z;
    o.w = (v.w - mu) * rstd * gg.w + bb.w;
    ((float4*)(out + (size_t)row * D_MODEL))[t] = o;
}

// ---------------------------------------------------------------- launch
extern "C" void kernel_launch(void* const* d_in, const int* in_sizes, int n_in,
                              void* d_out, int out_size, void* d_ws, size_t ws_size,
                              hipStream_t stream) {
    const float* batch = (const float*)d_in[0];
    const float* wq = (const float*)d_in[1];
    const float* bq = (const float*)d_in[2];
    const float* wk = (const float*)d_in[3];
    const float* bk = (const float*)d_in[4];
    const float* wv = (const float*)d_in[5];
    const float* bv = (const float*)d_in[6];
    const float* wo = (const float*)d_in[7];
    const float* bo = (const float*)d_in[8];
    const float* ln_g = (const float*)d_in[9];
    const float* ln_b = (const float*)d_in[10];
    float* out = (float*)d_out;

    char* ws = (char*)d_ws;
    size_t offXb   = 0;                                          // bf16 X (later Vt)
    size_t offWqkv = offXb + (size_t)ROWS * D_MODEL * 2;
    size_t offWo   = offWqkv + (size_t)3072 * 1024 * 2;
    size_t offBias = offWo + (size_t)1024 * 1024 * 2;
    size_t offQKV  = offBias + 3072 * 4;                         // bf16 qkv (later fp32 y)
    size_t offAttn = offQKV + (size_t)ROWS * 3072 * 2;
    size_t total   = offAttn + (size_t)ROWS * D_MODEL * 2;       // = 92,286,976
    if (ws_size < total) return;

    bf16_t* Xb   = (bf16_t*)(ws + offXb);
    bf16_t* Vt   = (bf16_t*)(ws + offXb);
    bf16_t* Wqkv = (bf16_t*)(ws + offWqkv);
    bf16_t* Wob  = (bf16_t*)(ws + offWo);
    float*  bqkv = (float*)(ws + offBias);
    bf16_t* qkv  = (bf16_t*)(ws + offQKV);
    float*  y    = (float*)(ws + offQKV);
    bf16_t* attn = (bf16_t*)(ws + offAttn);

    const float SC = 0.125f * 1.44269504088896f;  // 1/sqrt(64) * log2(e), folded into Q

    k_prep<<<2048, 256, 0, stream>>>(batch, wq, wk, wv, wo, bq, bk, bv,
                                     Xb, Wqkv, Wob, bqkv);
    k_gemm256<<<384, 512, 0, stream>>>(Xb, Wqkv, bqkv, qkv, SC);
    k_transpose_v<<<2048, 256, 0, stream>>>(qkv, Vt);
    k_attn<<<1024, 256, 0, stream>>>(qkv, Vt, attn);
    k_gemm_bt<<<64 * 8, 256, 0, stream>>>(attn, Wob, bo, batch, nullptr, y,
                                          8192, 1024, 1024, 0, 1.0f);
    k_layernorm<<<8192, 256, 0, stream>>>(y, ln_g, ln_b, out);
}